// Round 9
// baseline (140.491 us; speedup 1.0000x reference)
//
#include <hip/hip_runtime.h>

#define M 64
#define FG_T 0.6f
#define BG_T 0.4f

// packed column entry: (iou_bits << 32) | ~n — iou in (0,1] so the bit pattern
// is monotone; ties in iou resolve to SMALLER n (first occurrence = np argmax).
// 0 = "no entry"; fixup decodes p==0 -> anchor 0 (np argmax of an all-zero col).

__device__ inline float readlane_f(float v, int lane) {
    return __uint_as_float(__builtin_amdgcn_readlane(__float_as_uint(v), (unsigned)lane));
}

// -------- lb kernel: per-(b,m) lower bound on the column max + ws init ------
// For GT m, evaluate the EXACT iou (same op order as everywhere) of the 54 db
// anchors at the grid cell nearest the GT center (6 levels x 9 shapes). Each is
// a real anchor's iou -> max over them is a guaranteed lower bound on the
// column max (lb > 0 always: L5 whole-image anchors intersect every GT).
__global__ __launch_bounds__(64) void lb_kernel(
    const float* __restrict__ gt,    // [B, M, 4] xyxy
    const float* __restrict__ db,    // [N, 4] xywh
    float* __restrict__ lb,          // [B, M]
    unsigned long long* __restrict__ col)  // [B, M] — zero-initialized here
{
#pragma clang fp contract(off)
    const int b = blockIdx.x;
    const int m = threadIdx.x;

    col[b * M + m] = 0ull;

    const float4 g = ((const float4*)gt)[b * M + m];
    const float area_g = (g.z - g.x) * (g.w - g.y);   // reference op order
    const float gcx = (g.x + g.z) * 0.5f;
    const float gcy = (g.y + g.w) * 0.5f;

    const int   fms[6]  = {64, 32, 16, 8, 4, 2};
    const float stp[6]  = {8.0f, 16.0f, 32.0f, 64.0f, 128.0f, 256.0f};
    const int   off[6]  = {0, 36864, 46080, 48384, 48960, 49104};

    float best = 0.0f;
    #pragma unroll
    for (int i = 0; i < 6; ++i) {
        int fx = fms[i];
        int x = (int)(gcx / stp[i]); x = min(max(x, 0), fx - 1);
        int y = (int)(gcy / stp[i]); y = min(max(y, 0), fx - 1);
        int base = off[i] + (y * fx + x) * 9;
        for (int a = 0; a < 9; ++a) {
            float4 d = ((const float4*)db)[base + a];
            float ax0 = d.x - d.z / 2.0f;
            float ay0 = d.y - d.w / 2.0f;
            float ax1 = d.x + d.z / 2.0f;
            float ay1 = d.y + d.w / 2.0f;
            float area_a = (ax1 - ax0) * (ay1 - ay0);
            float ltx = fmaxf(ax0, g.x);
            float lty = fmaxf(ay0, g.y);
            float rbx = fminf(ax1, g.z);
            float rby = fminf(ay1, g.w);
            float w = fmaxf(rbx - ltx, 0.0f);
            float h = fmaxf(rby - lty, 0.0f);
            float inter = w * h;
            float iou = inter / ((area_a + area_g) - inter);  // exact anchor iou
            best = fmaxf(best, iou);
        }
    }
    lb[b * M + m] = best;
}

// ------- row kernel: 2 anchors per lane, branchless inner loop -------
// Latency-bound before (r8 counters: 2790 VALU cy/wave but 6200 cy wall, occ
// 25%): each candidate-m iteration was a serial readlane->IoU->div->cndmask
// chain. Two anchors per lane share the readlanes/mask/branch overhead and
// give two independent chains to interleave; the __any(inter>0) branch is
// dropped (iou=+0.0 can't beat best=0 under strict >, can't pass iou>=lb>0).
__global__ __launch_bounds__(256) void row_kernel(
    const float* __restrict__ gt,    // [B, M, 4] xyxy
    const int*   __restrict__ lab,   // [B, M]
    const float* __restrict__ db,    // [N, 4] xywh
    const float* __restrict__ lb,    // [B, M] column-max lower bound
    float* __restrict__ out_loc,     // [B, N, 4]
    float* __restrict__ out_cls,     // [B, N]
    unsigned long long* __restrict__ col,  // [B, M] packed column max
    int N)
{
#pragma clang fp contract(off)
    const int b    = blockIdx.y;
    const int tid  = threadIdx.x;
    const int lane = tid & 63;
    const int wv   = tid >> 6;
    const float4* __restrict__ gtb = (const float4*)gt + b * M;

    // Heavy coarse-level blocks first (reversal — neutral in r8 but harmless).
    const int  chunk = gridDim.x - 1 - blockIdx.x;
    // wave covers 128 consecutive anchors; lane owns n0 and n1 = n0+64
    const int  n0 = chunk * 512 + wv * 128 + lane;
    const int  n1 = n0 + 64;
    const bool valid0 = (n0 < N);
    const bool valid1 = (n1 < N);
    const int  nl0 = valid0 ? n0 : (N - 1);
    const int  nl1 = valid1 ? n1 : (N - 1);

    const float4 d0 = ((const float4*)db)[nl0];
    const float4 d1 = ((const float4*)db)[nl1];
    // db_xyxy exactly as reference: c - wh/2, c + wh/2 (div by 2 is exact)
    const float a0x0 = d0.x - d0.z / 2.0f, a0y0 = d0.y - d0.w / 2.0f;
    const float a0x1 = d0.x + d0.z / 2.0f, a0y1 = d0.y + d0.w / 2.0f;
    const float a1x0 = d1.x - d1.z / 2.0f, a1y0 = d1.y - d1.w / 2.0f;
    const float a1x1 = d1.x + d1.z / 2.0f, a1y1 = d1.y + d1.w / 2.0f;
    const float area0 = (a0x1 - a0x0) * (a0y1 - a0y0);
    const float area1 = (a1x1 - a1x0) * (a1y1 - a1y0);

    // wave bbox = union of the wave's 128 anchors
    float wx0 = fminf(a0x0, a1x0), wy0 = fminf(a0y0, a1y0);
    float wx1 = fmaxf(a0x1, a1x1), wy1 = fmaxf(a0y1, a1y1);
    #pragma unroll
    for (int off = 1; off < 64; off <<= 1) {
        wx0 = fminf(wx0, __shfl_xor(wx0, off));
        wy0 = fminf(wy0, __shfl_xor(wy0, off));
        wx1 = fmaxf(wx1, __shfl_xor(wx1, off));
        wy1 = fmaxf(wy1, __shfl_xor(wy1, off));
    }

    // lane l caches GT l (+ area, lb) in registers for readlane broadcast;
    // candidate iff GT strictly overlaps wave bbox (touch-only => inter==0 =>
    // iou==0 => irrelevant for both row argmax and column candidates).
    const float4 gl = gtb[lane];
    const float  area_l = (gl.z - gl.x) * (gl.w - gl.y);  // reference op order
    const float  lbl    = lb[b * M + lane];
    const bool cand = (gl.x < wx1) && (gl.z > wx0) && (gl.y < wy1) && (gl.w > wy0);
    unsigned long long mask = __ballot((int)cand);

    // best=0, bi=0: all-zero row keeps bi=0 (np argmax); strict > = first max.
    float best0 = 0.0f, best1 = 0.0f;
    int   bi0   = 0,    bi1   = 0;

    while (mask) {
        const int m = __builtin_amdgcn_readfirstlane(__builtin_ctzll(mask));
        mask &= mask - 1;
        // GT m fragments pulled from lane m's registers (v_readlane -> SGPR)
        const float gx0 = readlane_f(gl.x, m);
        const float gy0 = readlane_f(gl.y, m);
        const float gx1 = readlane_f(gl.z, m);
        const float gy1 = readlane_f(gl.w, m);
        const float ab  = readlane_f(area_l, m);
        const float lbm = readlane_f(lbl, m);

        // anchor 0 — IEEE div: bit-exact vs np
        float i0 = fmaxf(fminf(a0x1, gx1) - fmaxf(a0x0, gx0), 0.0f)
                 * fmaxf(fminf(a0y1, gy1) - fmaxf(a0y0, gy0), 0.0f);
        // anchor 1 — independent chain, interleaves with anchor 0
        float i1 = fmaxf(fminf(a1x1, gx1) - fmaxf(a1x0, gx0), 0.0f)
                 * fmaxf(fminf(a1y1, gy1) - fmaxf(a1y0, gy0), 0.0f);

        float iou0 = i0 / ((area0 + ab) - i0);
        float iou1 = i1 / ((area1 + ab) - i1);

        if (iou0 > best0) { best0 = iou0; bi0 = m; }
        if (iou1 > best1) { best1 = iou1; bi1 = m; }

        // Column candidates: iou >= lb[m] (lb <= column max by construction) —
        // catches the argmax and all earlier ties; rare => cheap skipped branch.
        if (valid0 && iou0 >= lbm) {
            unsigned long long p =
                (((unsigned long long)__float_as_uint(iou0)) << 32)
                | (unsigned int)(~(unsigned int)n0);
            atomicMax(&col[b * M + m], p);
        }
        if (valid1 && iou1 >= lbm) {
            unsigned long long p =
                (((unsigned long long)__float_as_uint(iou1)) << 32)
                | (unsigned int)(~(unsigned int)n1);
            atomicMax(&col[b * M + m], p);
        }
    }

    // epilogue: encode both anchors. rcp-based math is fine here (ordering
    // decided above; absmax threshold 3.54 vs ~1e-5 rcp error).
    #pragma unroll
    for (int k = 0; k < 2; ++k) {
        const bool  valid = k ? valid1 : valid0;
        if (!valid) continue;
        const int   n    = k ? n1 : n0;
        const float best = k ? best1 : best0;
        const int   bi   = k ? bi1 : bi0;
        const float4 d   = k ? d1 : d0;

        float cv;
        if (best < BG_T)      cv = 0.0f;
        else if (best < FG_T) cv = -1.0f;
        else                  cv = (float)(lab[b * M + bi] + 1);

        float4 g = gtb[bi];   // divergent gather, tiny table, L1-resident
        float bcx = (g.x + g.z) * 0.5f;
        float bcy = (g.y + g.w) * 0.5f;
        float bw  = g.z - g.x;
        float bh  = g.w - g.y;
        float rz  = __builtin_amdgcn_rcpf(d.z);
        float rw  = __builtin_amdgcn_rcpf(d.w);
        float lx = (bcx - d.x) * rz * 10.0f;
        float ly = (bcy - d.y) * rw * 10.0f;
        float lw = __logf(bw * rz) * 5.0f;
        float lh = __logf(bh * rw) * 5.0f;

        ((float4*)out_loc)[(size_t)b * N + n] = make_float4(lx, ly, lw, lh);
        out_cls[(size_t)b * N + n] = cv;
    }
}

// Apply the best_p_idx override: best_t_idx[best_p[m]] = m (last write wins),
// best_t -> 2.0 so cls = lab+1 and loc re-encoded from gt[m]. Separate dispatch:
// the kernel boundary provides cross-XCD coherence for free — fusing this with
// device-scope fences cost 4.5x (r7).
__global__ void fixup_kernel(
    const float* __restrict__ gt,
    const int*   __restrict__ lab,
    const float* __restrict__ db,
    const unsigned long long* __restrict__ col,
    float* __restrict__ out_loc,
    float* __restrict__ out_cls,
    int N)
{
#pragma clang fp contract(off)
    __shared__ int s_a[M];
    const int b = blockIdx.x;
    const int m = threadIdx.x;  // 64 threads

    unsigned long long p = col[b * M + m];
    // p==0: no anchor overlapped GT m -> np argmax of all-zero column = 0.
    int a = (p == 0ull) ? 0 : (int)(~(unsigned int)(p & 0xFFFFFFFFull));
    s_a[m] = a;
    __syncthreads();

    // last-write-wins for duplicate anchors (np fancy assignment semantics)
    bool write = true;
    for (int mm = m + 1; mm < M; ++mm) {
        if (s_a[mm] == a) { write = false; break; }
    }
    if (write) {
        float4 d = ((const float4*)db)[a];
        float4 g = ((const float4*)gt)[b * M + m];
        float bcx = (g.x + g.z) / 2.0f;
        float bcy = (g.y + g.w) / 2.0f;
        float bw  = g.z - g.x;
        float bh  = g.w - g.y;
        float lx = ((bcx - d.x) / d.z) / 0.1f;
        float ly = ((bcy - d.y) / d.w) / 0.1f;
        float lw = __logf(bw / d.z) / 0.2f;
        float lh = __logf(bh / d.w) / 0.2f;

        ((float4*)out_loc)[(size_t)b * N + a] = make_float4(lx, ly, lw, lh);
        out_cls[(size_t)b * N + a] = (float)(lab[b * M + m] + 1);  // best_t = 2.0
    }
}

extern "C" void kernel_launch(void* const* d_in, const int* in_sizes, int n_in,
                              void* d_out, int out_size, void* d_ws, size_t ws_size,
                              hipStream_t stream) {
    const float* gt  = (const float*)d_in[0];   // gt_boxes  [B, M, 4] xyxy
    const int*   lab = (const int*)d_in[1];     // labels    [B, M]
    const float* db  = (const float*)d_in[2];   // default_boxes [N, 4] xywh

    const int B = in_sizes[1] / M;
    const int N = in_sizes[2] / 4;

    float* out_loc = (float*)d_out;                       // [B, N, 4]
    float* out_cls = out_loc + (size_t)B * N * 4;         // [B, N]

    unsigned long long* col = (unsigned long long*)d_ws;          // [B, M] u64
    float*              lbp = (float*)(col + (size_t)B * M);      // [B, M] f32

    lb_kernel<<<dim3(B), dim3(M), 0, stream>>>(gt, db, lbp, col);
    row_kernel<<<dim3((N + 511) / 512, B), dim3(256), 0, stream>>>(
        gt, lab, db, lbp, out_loc, out_cls, col, N);
    fixup_kernel<<<dim3(B), dim3(M), 0, stream>>>(gt, lab, db, col, out_loc, out_cls, N);
}

// Round 10
// 120.805 us; speedup vs baseline: 1.1630x; 1.1630x over previous
//
#include <hip/hip_runtime.h>

#define M 64
#define FG_T 0.6f
#define BG_T 0.4f

// packed column entry: (iou_bits << 32) | ~n — iou in (0,1] so the bit pattern
// is monotone; ties in iou resolve to SMALLER n (first occurrence = np argmax).
// 0 = "no entry"; fixup decodes p==0 -> anchor 0 (np argmax of an all-zero col).

__device__ inline float readlane_f(float v, int lane) {
    return __uint_as_float(__builtin_amdgcn_readlane(__float_as_uint(v), (unsigned)lane));
}

// -------- lb kernel: per-(b,m) lower bound on the column max + ws init ------
// One wave per (b,m): lanes 0..53 each evaluate the EXACT iou (same op order
// as everywhere) of one of the 54 db anchors at the grid cell nearest the GT
// center (6 levels x 9 shapes); 6-step shuffle max. Each candidate is a real
// anchor's iou -> guaranteed lower bound on the column max; the nearest L5
// (384px) anchor always intersects (|gc - c| <= 128 < 192 half-extent), so
// lb > 0 for every GT.
__global__ __launch_bounds__(64) void lb_kernel(
    const float* __restrict__ gt,    // [B, M, 4] xyxy
    const float* __restrict__ db,    // [N, 4] xywh
    float* __restrict__ lb,          // [B, M]
    unsigned long long* __restrict__ col)  // [B, M] — zero-initialized here
{
#pragma clang fp contract(off)
    const int bm = blockIdx.x;       // b*M + m
    const int t  = threadIdx.x;

    if (t == 0) col[bm] = 0ull;

    const float4 g = ((const float4*)gt)[bm];
    const float area_g = (g.z - g.x) * (g.w - g.y);   // reference op order
    const float gcx = (g.x + g.z) * 0.5f;
    const float gcy = (g.y + g.w) * 0.5f;

    const int   fms[6] = {64, 32, 16, 8, 4, 2};
    const float stp[6] = {8.0f, 16.0f, 32.0f, 64.0f, 128.0f, 256.0f};
    const int   off[6] = {0, 36864, 46080, 48384, 48960, 49104};

    float iou = 0.0f;
    if (t < 54) {
        const int lev = t / 9, a = t - lev * 9;
        const int fx  = fms[lev];
        int x = (int)(gcx / stp[lev]); x = min(max(x, 0), fx - 1);
        int y = (int)(gcy / stp[lev]); y = min(max(y, 0), fx - 1);
        const float4 d = ((const float4*)db)[off[lev] + (y * fx + x) * 9 + a];
        float ax0 = d.x - d.z / 2.0f;
        float ay0 = d.y - d.w / 2.0f;
        float ax1 = d.x + d.z / 2.0f;
        float ay1 = d.y + d.w / 2.0f;
        float area_a = (ax1 - ax0) * (ay1 - ay0);
        float w = fmaxf(fminf(ax1, g.z) - fmaxf(ax0, g.x), 0.0f);
        float h = fmaxf(fminf(ay1, g.w) - fmaxf(ay0, g.y), 0.0f);
        float inter = w * h;
        iou = inter / ((area_a + area_g) - inter);    // exact anchor iou
    }
    #pragma unroll
    for (int o = 1; o < 64; o <<= 1) iou = fmaxf(iou, __shfl_xor(iou, o));
    if (t == 0) lb[bm] = iou;
}

// ------- row kernel: per-anchor best GT + column candidates (r8 structure,
// mask-walk unrolled by 2 GTs) -------
// r9 lesson: keep 1 anchor/lane (small bbox, max waves); the only safe ILP is
// across two GTs of the SAME anchor — candidate count and bbox unchanged,
// per-iteration overhead (ctz/readfirstlane/ballot/branch) halved, pre-div
// chains interleave (div tails still serialize on VCC — accepted).
__global__ __launch_bounds__(256) void row_kernel(
    const float* __restrict__ gt,    // [B, M, 4] xyxy
    const int*   __restrict__ lab,   // [B, M]
    const float* __restrict__ db,    // [N, 4] xywh
    const float* __restrict__ lb,    // [B, M] column-max lower bound
    float* __restrict__ out_loc,     // [B, N, 4]
    float* __restrict__ out_cls,     // [B, N]
    unsigned long long* __restrict__ col,  // [B, M] packed column max
    int N)
{
#pragma clang fp contract(off)
    const int b   = blockIdx.y;
    const int tid = threadIdx.x;
    const float4* __restrict__ gtb = (const float4*)gt + b * M;

    // Heavy coarse-level blocks first (neutral in r8, harmless).
    const int  chunk = gridDim.x - 1 - blockIdx.x;
    const int  n     = chunk * 256 + tid;
    const bool valid = (n < N);
    const int  nl    = valid ? n : (N - 1);

    const float4 d = ((const float4*)db)[nl];
    // db_xyxy exactly as reference: c - wh/2, c + wh/2 (div by 2 is exact)
    const float ax0 = d.x - d.z / 2.0f;
    const float ay0 = d.y - d.w / 2.0f;
    const float ax1 = d.x + d.z / 2.0f;
    const float ay1 = d.y + d.w / 2.0f;
    const float area_a = (ax1 - ax0) * (ay1 - ay0);

    // one-time wave bbox (union of the wave's 64 anchors)
    float wx0 = ax0, wy0 = ay0, wx1 = ax1, wy1 = ay1;
    #pragma unroll
    for (int o = 1; o < 64; o <<= 1) {
        wx0 = fminf(wx0, __shfl_xor(wx0, o));
        wy0 = fminf(wy0, __shfl_xor(wy0, o));
        wx1 = fmaxf(wx1, __shfl_xor(wx1, o));
        wy1 = fmaxf(wy1, __shfl_xor(wy1, o));
    }

    // lane l caches GT l (+ area, lb) in registers for readlane broadcast;
    // candidate iff GT strictly overlaps wave bbox (touch-only => inter==0 =>
    // iou==0 => irrelevant for both row argmax and column candidates).
    const int    l  = tid & 63;
    const float4 gl = gtb[l];
    const float  area_l = (gl.z - gl.x) * (gl.w - gl.y);  // reference op order
    const float  lbl    = lb[b * M + l];
    const bool cand = (gl.x < wx1) && (gl.z > wx0) && (gl.y < wy1) && (gl.w > wy0);
    unsigned long long mask = __ballot((int)cand);

    // best=0, bi=0: all-zero row keeps bi=0 (np argmax); strict > = first max.
    float best = 0.0f;
    int   bi   = 0;

    while (mask) {
        const int m0 = __builtin_amdgcn_readfirstlane(__builtin_ctzll(mask));
        mask &= mask - 1;
        const bool has2 = (mask != 0ull);
        const int m1 = has2 ? __builtin_amdgcn_readfirstlane(__builtin_ctzll(mask)) : m0;
        if (has2) mask &= mask - 1;

        // GT fragments pulled from lanes m0/m1 (v_readlane -> SGPR, independent)
        const float g0x0 = readlane_f(gl.x, m0), g0y0 = readlane_f(gl.y, m0);
        const float g0x1 = readlane_f(gl.z, m0), g0y1 = readlane_f(gl.w, m0);
        const float ab0  = readlane_f(area_l, m0);
        const float g1x0 = readlane_f(gl.x, m1), g1y0 = readlane_f(gl.y, m1);
        const float g1x1 = readlane_f(gl.z, m1), g1y1 = readlane_f(gl.w, m1);
        const float ab1  = readlane_f(area_l, m1);

        // two independent intersection chains (no VCC hazard here)
        float i0 = fmaxf(fminf(ax1, g0x1) - fmaxf(ax0, g0x0), 0.0f)
                 * fmaxf(fminf(ay1, g0y1) - fmaxf(ay0, g0y0), 0.0f);
        float i1 = fmaxf(fminf(ax1, g1x1) - fmaxf(ax0, g1x0), 0.0f)
                 * fmaxf(fminf(ay1, g1y1) - fmaxf(ay0, g1y0), 0.0f);

        if (__any((i0 > 0.0f) || (i1 > 0.0f))) {
            const float lb0 = readlane_f(lbl, m0);
            const float lb1 = readlane_f(lbl, m1);
            // IEEE div: bit-exact vs np; inter==0 lanes get iou=+0.0 which can
            // neither beat best=0 (strict >) nor pass iou>=lb>0.
            float iou0 = i0 / ((area_a + ab0) - i0);
            float iou1 = i1 / ((area_a + ab1) - i1);

            // m0 < m1 always; process in order => first-occurrence argmax.
            if (iou0 > best)         { best = iou0; bi = m0; }
            if (has2 && iou1 > best) { best = iou1; bi = m1; }

            // Column candidates: iou >= lb[m] (lb <= column max by
            // construction) — catches the argmax and all earlier ties; rare.
            if (valid && iou0 >= lb0) {
                unsigned long long p =
                    (((unsigned long long)__float_as_uint(iou0)) << 32)
                    | (unsigned int)(~(unsigned int)n);
                atomicMax(&col[b * M + m0], p);
            }
            if (has2 && valid && iou1 >= lb1) {
                unsigned long long p =
                    (((unsigned long long)__float_as_uint(iou1)) << 32)
                    | (unsigned int)(~(unsigned int)n);
                atomicMax(&col[b * M + m1], p);
            }
        }
    }

    if (valid) {
        float cv;
        if (best < BG_T)      cv = 0.0f;
        else if (best < FG_T) cv = -1.0f;
        else                  cv = (float)(lab[b * M + bi] + 1);

        float4 g = gtb[bi];   // divergent gather, tiny table, L1-resident
        // rcp/log epilogue: ordering decided above; absmax threshold 3.54 vs
        // ~1e-5 rcp error (validated r9: absmax unchanged at 0.03125).
        float bcx = (g.x + g.z) * 0.5f;
        float bcy = (g.y + g.w) * 0.5f;
        float bw  = g.z - g.x;
        float bh  = g.w - g.y;
        float rz  = __builtin_amdgcn_rcpf(d.z);
        float rw  = __builtin_amdgcn_rcpf(d.w);
        float lx = (bcx - d.x) * rz * 10.0f;
        float ly = (bcy - d.y) * rw * 10.0f;
        float lw = __logf(bw * rz) * 5.0f;
        float lh = __logf(bh * rw) * 5.0f;

        ((float4*)out_loc)[(size_t)b * N + n] = make_float4(lx, ly, lw, lh);
        out_cls[(size_t)b * N + n] = cv;
    }
}

// Apply the best_p_idx override: best_t_idx[best_p[m]] = m (last write wins),
// best_t -> 2.0 so cls = lab+1 and loc re-encoded from gt[m]. Separate dispatch:
// the kernel boundary provides cross-XCD coherence for free — fusing this with
// device-scope fences cost 4.5x (r7).
__global__ void fixup_kernel(
    const float* __restrict__ gt,
    const int*   __restrict__ lab,
    const float* __restrict__ db,
    const unsigned long long* __restrict__ col,
    float* __restrict__ out_loc,
    float* __restrict__ out_cls,
    int N)
{
#pragma clang fp contract(off)
    __shared__ int s_a[M];
    const int b = blockIdx.x;
    const int m = threadIdx.x;  // 64 threads

    unsigned long long p = col[b * M + m];
    // p==0: no anchor overlapped GT m -> np argmax of all-zero column = 0.
    int a = (p == 0ull) ? 0 : (int)(~(unsigned int)(p & 0xFFFFFFFFull));
    s_a[m] = a;
    __syncthreads();

    // last-write-wins for duplicate anchors (np fancy assignment semantics)
    bool write = true;
    for (int mm = m + 1; mm < M; ++mm) {
        if (s_a[mm] == a) { write = false; break; }
    }
    if (write) {
        float4 d = ((const float4*)db)[a];
        float4 g = ((const float4*)gt)[b * M + m];
        float bcx = (g.x + g.z) / 2.0f;
        float bcy = (g.y + g.w) / 2.0f;
        float bw  = g.z - g.x;
        float bh  = g.w - g.y;
        float lx = ((bcx - d.x) / d.z) / 0.1f;
        float ly = ((bcy - d.y) / d.w) / 0.1f;
        float lw = __logf(bw / d.z) / 0.2f;
        float lh = __logf(bh / d.w) / 0.2f;

        ((float4*)out_loc)[(size_t)b * N + a] = make_float4(lx, ly, lw, lh);
        out_cls[(size_t)b * N + a] = (float)(lab[b * M + m] + 1);  // best_t = 2.0
    }
}

extern "C" void kernel_launch(void* const* d_in, const int* in_sizes, int n_in,
                              void* d_out, int out_size, void* d_ws, size_t ws_size,
                              hipStream_t stream) {
    const float* gt  = (const float*)d_in[0];   // gt_boxes  [B, M, 4] xyxy
    const int*   lab = (const int*)d_in[1];     // labels    [B, M]
    const float* db  = (const float*)d_in[2];   // default_boxes [N, 4] xywh

    const int B = in_sizes[1] / M;
    const int N = in_sizes[2] / 4;

    float* out_loc = (float*)d_out;                       // [B, N, 4]
    float* out_cls = out_loc + (size_t)B * N * 4;         // [B, N]

    unsigned long long* col = (unsigned long long*)d_ws;          // [B, M] u64
    float*              lbp = (float*)(col + (size_t)B * M);      // [B, M] f32

    lb_kernel<<<dim3(B * M), dim3(64), 0, stream>>>(gt, db, lbp, col);
    row_kernel<<<dim3((N + 255) / 256, B), dim3(256), 0, stream>>>(
        gt, lab, db, lbp, out_loc, out_cls, col, N);
    fixup_kernel<<<dim3(B), dim3(M), 0, stream>>>(gt, lab, db, col, out_loc, out_cls, N);
}

// Round 11
// 105.326 us; speedup vs baseline: 1.3339x; 1.1470x over previous
//
#include <hip/hip_runtime.h>

#define M 64
#define FG_T 0.6f
#define BG_T 0.4f
#define PERSIST_BLOCKS 2048   // 8 blocks/CU x 256 CUs = device capacity at 16 VGPR

// packed column entry: (iou_bits << 32) | ~n — iou in (0,1] so the bit pattern
// is monotone; ties in iou resolve to SMALLER n (first occurrence = np argmax).
// 0 = "no entry"; fixup decodes p==0 -> anchor 0 (np argmax of an all-zero col).

__device__ inline float readlane_f(float v, int lane) {
    return __uint_as_float(__builtin_amdgcn_readlane(__float_as_uint(v), (unsigned)lane));
}

// -------- lb kernel: per-(b,m) lower bound on the column max + ws init ------
// One wave per (b,m): lanes 0..53 each evaluate the EXACT iou (same op order
// as everywhere) of one of the 54 db anchors at the grid cell nearest the GT
// center (6 levels x 9 shapes); 6-step shuffle max. Each candidate is a real
// anchor's iou -> guaranteed lower bound on the column max; the nearest L5
// (384px) anchor always intersects, so lb > 0 for every GT.
__global__ __launch_bounds__(64) void lb_kernel(
    const float* __restrict__ gt,    // [B, M, 4] xyxy
    const float* __restrict__ db,    // [N, 4] xywh
    float* __restrict__ lb,          // [B, M]
    unsigned long long* __restrict__ col)  // [B, M] — zero-initialized here
{
#pragma clang fp contract(off)
    const int bm = blockIdx.x;       // b*M + m
    const int t  = threadIdx.x;

    if (t == 0) col[bm] = 0ull;

    const float4 g = ((const float4*)gt)[bm];
    const float area_g = (g.z - g.x) * (g.w - g.y);   // reference op order
    const float gcx = (g.x + g.z) * 0.5f;
    const float gcy = (g.y + g.w) * 0.5f;

    const int   fms[6] = {64, 32, 16, 8, 4, 2};
    const float stp[6] = {8.0f, 16.0f, 32.0f, 64.0f, 128.0f, 256.0f};
    const int   off[6] = {0, 36864, 46080, 48384, 48960, 49104};

    float iou = 0.0f;
    if (t < 54) {
        const int lev = t / 9, a = t - lev * 9;
        const int fx  = fms[lev];
        int x = (int)(gcx / stp[lev]); x = min(max(x, 0), fx - 1);
        int y = (int)(gcy / stp[lev]); y = min(max(y, 0), fx - 1);
        const float4 d = ((const float4*)db)[off[lev] + (y * fx + x) * 9 + a];
        float ax0 = d.x - d.z / 2.0f;
        float ay0 = d.y - d.w / 2.0f;
        float ax1 = d.x + d.z / 2.0f;
        float ay1 = d.y + d.w / 2.0f;
        float area_a = (ax1 - ax0) * (ay1 - ay0);
        float w = fmaxf(fminf(ax1, g.z) - fmaxf(ax0, g.x), 0.0f);
        float h = fmaxf(fminf(ay1, g.w) - fmaxf(ay0, g.y), 0.0f);
        float inter = w * h;
        iou = inter / ((area_a + area_g) - inter);    // exact anchor iou
    }
    #pragma unroll
    for (int o = 1; o < 64; o <<= 1) iou = fmaxf(iou, __shfl_xor(iou, o));
    if (t == 0) lb[bm] = iou;
}

// ------- row kernel: PERSISTENT grid-stride over (batch, chunk) units -------
// r10 counters: 6176 short blocks kept only ~2 waves/SIMD resident (occ 26%,
// VALUBusy 43%, wave wall ~5x its issue time) — launched TLP never became
// resident TLP. Persistent blocks at device capacity keep ~8 waves/SIMD for
// the whole kernel so the serial div-tail chains of 8 waves interleave.
// Units are chunk-major with coarse-level (heavy, high-n) chunks first.
__global__ __launch_bounds__(256) void row_kernel(
    const float* __restrict__ gt,    // [B, M, 4] xyxy
    const int*   __restrict__ lab,   // [B, M]
    const float* __restrict__ db,    // [N, 4] xywh
    const float* __restrict__ lb,    // [B, M] column-max lower bound
    float* __restrict__ out_loc,     // [B, N, 4]
    float* __restrict__ out_cls,     // [B, N]
    unsigned long long* __restrict__ col,  // [B, M] packed column max
    int N, int B, int nch)           // nch = ceil(N/256)
{
#pragma clang fp contract(off)
    const int tid   = threadIdx.x;
    const int lane  = tid & 63;
    const int total = nch * B;

    for (int u = blockIdx.x; u < total; u += gridDim.x) {
        // chunk-major: u/B = reversed chunk (heavy coarse levels first), u%B = batch
        const unsigned uu = (unsigned)u;
        const int cm    = (int)(uu / (unsigned)B);
        const int b     = (int)(uu - (unsigned)cm * (unsigned)B);
        const int chunk = nch - 1 - cm;
        const float4* __restrict__ gtb = (const float4*)gt + b * M;

        const int  n     = chunk * 256 + tid;
        const bool valid = (n < N);
        const int  nl    = valid ? n : (N - 1);

        const float4 d = ((const float4*)db)[nl];
        // db_xyxy exactly as reference: c - wh/2, c + wh/2 (div by 2 is exact)
        const float ax0 = d.x - d.z / 2.0f;
        const float ay0 = d.y - d.w / 2.0f;
        const float ax1 = d.x + d.z / 2.0f;
        const float ay1 = d.y + d.w / 2.0f;
        const float area_a = (ax1 - ax0) * (ay1 - ay0);

        // wave bbox (union of the wave's 64 anchors)
        float wx0 = ax0, wy0 = ay0, wx1 = ax1, wy1 = ay1;
        #pragma unroll
        for (int o = 1; o < 64; o <<= 1) {
            wx0 = fminf(wx0, __shfl_xor(wx0, o));
            wy0 = fminf(wy0, __shfl_xor(wy0, o));
            wx1 = fmaxf(wx1, __shfl_xor(wx1, o));
            wy1 = fmaxf(wy1, __shfl_xor(wy1, o));
        }

        // lane l caches GT l (+ area, lb) in registers for readlane broadcast;
        // candidate iff GT strictly overlaps wave bbox (touch-only => inter==0
        // => iou==0 => irrelevant for row argmax and column candidates).
        const float4 gl = gtb[lane];
        const float  area_l = (gl.z - gl.x) * (gl.w - gl.y);  // reference op order
        const float  lbl    = lb[b * M + lane];
        const bool cand = (gl.x < wx1) && (gl.z > wx0) && (gl.y < wy1) && (gl.w > wy0);
        unsigned long long mask = __ballot((int)cand);

        // best=0, bi=0: all-zero row keeps bi=0 (np argmax); strict > = first max.
        float best = 0.0f;
        int   bi   = 0;

        while (mask) {
            const int m0 = __builtin_amdgcn_readfirstlane(__builtin_ctzll(mask));
            mask &= mask - 1;
            const bool has2 = (mask != 0ull);
            const int m1 = has2 ? __builtin_amdgcn_readfirstlane(__builtin_ctzll(mask)) : m0;
            if (has2) mask &= mask - 1;

            // GT fragments pulled from lanes m0/m1 (v_readlane -> SGPR, independent)
            const float g0x0 = readlane_f(gl.x, m0), g0y0 = readlane_f(gl.y, m0);
            const float g0x1 = readlane_f(gl.z, m0), g0y1 = readlane_f(gl.w, m0);
            const float ab0  = readlane_f(area_l, m0);
            const float g1x0 = readlane_f(gl.x, m1), g1y0 = readlane_f(gl.y, m1);
            const float g1x1 = readlane_f(gl.z, m1), g1y1 = readlane_f(gl.w, m1);
            const float ab1  = readlane_f(area_l, m1);

            // two independent intersection chains (no VCC hazard here)
            float i0 = fmaxf(fminf(ax1, g0x1) - fmaxf(ax0, g0x0), 0.0f)
                     * fmaxf(fminf(ay1, g0y1) - fmaxf(ay0, g0y0), 0.0f);
            float i1 = fmaxf(fminf(ax1, g1x1) - fmaxf(ax0, g1x0), 0.0f)
                     * fmaxf(fminf(ay1, g1y1) - fmaxf(ay0, g1y0), 0.0f);

            if (__any((i0 > 0.0f) || (i1 > 0.0f))) {
                const float lb0 = readlane_f(lbl, m0);
                const float lb1 = readlane_f(lbl, m1);
                // IEEE div: bit-exact vs np; inter==0 lanes get iou=+0.0 which
                // can neither beat best=0 (strict >) nor pass iou>=lb>0.
                float iou0 = i0 / ((area_a + ab0) - i0);
                float iou1 = i1 / ((area_a + ab1) - i1);

                // m0 < m1 always; process in order => first-occurrence argmax.
                if (iou0 > best)         { best = iou0; bi = m0; }
                if (has2 && iou1 > best) { best = iou1; bi = m1; }

                // Column candidates: iou >= lb[m] (lb <= column max by
                // construction) — catches the argmax and all earlier ties; rare.
                if (valid && iou0 >= lb0) {
                    unsigned long long p =
                        (((unsigned long long)__float_as_uint(iou0)) << 32)
                        | (unsigned int)(~(unsigned int)n);
                    atomicMax(&col[b * M + m0], p);
                }
                if (has2 && valid && iou1 >= lb1) {
                    unsigned long long p =
                        (((unsigned long long)__float_as_uint(iou1)) << 32)
                        | (unsigned int)(~(unsigned int)n);
                    atomicMax(&col[b * M + m1], p);
                }
            }
        }

        if (valid) {
            float cv;
            if (best < BG_T)      cv = 0.0f;
            else if (best < FG_T) cv = -1.0f;
            else                  cv = (float)(lab[b * M + bi] + 1);

            float4 g = gtb[bi];   // divergent gather, tiny table, L1-resident
            // rcp/log epilogue: ordering decided above; absmax threshold 3.54
            // vs ~1e-5 rcp error (validated r9/r10: absmax 0.03125 unchanged).
            float bcx = (g.x + g.z) * 0.5f;
            float bcy = (g.y + g.w) * 0.5f;
            float bw  = g.z - g.x;
            float bh  = g.w - g.y;
            float rz  = __builtin_amdgcn_rcpf(d.z);
            float rw  = __builtin_amdgcn_rcpf(d.w);
            float lx = (bcx - d.x) * rz * 10.0f;
            float ly = (bcy - d.y) * rw * 10.0f;
            float lw = __logf(bw * rz) * 5.0f;
            float lh = __logf(bh * rw) * 5.0f;

            ((float4*)out_loc)[(size_t)b * N + n] = make_float4(lx, ly, lw, lh);
            out_cls[(size_t)b * N + n] = cv;
        }
    }
}

// Apply the best_p_idx override: best_t_idx[best_p[m]] = m (last write wins),
// best_t -> 2.0 so cls = lab+1 and loc re-encoded from gt[m]. Separate dispatch:
// the kernel boundary provides cross-XCD coherence for free — fusing this with
// device-scope fences cost 4.5x (r7).
__global__ void fixup_kernel(
    const float* __restrict__ gt,
    const int*   __restrict__ lab,
    const float* __restrict__ db,
    const unsigned long long* __restrict__ col,
    float* __restrict__ out_loc,
    float* __restrict__ out_cls,
    int N)
{
#pragma clang fp contract(off)
    __shared__ int s_a[M];
    const int b = blockIdx.x;
    const int m = threadIdx.x;  // 64 threads

    unsigned long long p = col[b * M + m];
    // p==0: no anchor overlapped GT m -> np argmax of all-zero column = 0.
    int a = (p == 0ull) ? 0 : (int)(~(unsigned int)(p & 0xFFFFFFFFull));
    s_a[m] = a;
    __syncthreads();

    // last-write-wins for duplicate anchors (np fancy assignment semantics)
    bool write = true;
    for (int mm = m + 1; mm < M; ++mm) {
        if (s_a[mm] == a) { write = false; break; }
    }
    if (write) {
        float4 d = ((const float4*)db)[a];
        float4 g = ((const float4*)gt)[b * M + m];
        float bcx = (g.x + g.z) / 2.0f;
        float bcy = (g.y + g.w) / 2.0f;
        float bw  = g.z - g.x;
        float bh  = g.w - g.y;
        float lx = ((bcx - d.x) / d.z) / 0.1f;
        float ly = ((bcy - d.y) / d.w) / 0.1f;
        float lw = __logf(bw / d.z) / 0.2f;
        float lh = __logf(bh / d.w) / 0.2f;

        ((float4*)out_loc)[(size_t)b * N + a] = make_float4(lx, ly, lw, lh);
        out_cls[(size_t)b * N + a] = (float)(lab[b * M + m] + 1);  // best_t = 2.0
    }
}

extern "C" void kernel_launch(void* const* d_in, const int* in_sizes, int n_in,
                              void* d_out, int out_size, void* d_ws, size_t ws_size,
                              hipStream_t stream) {
    const float* gt  = (const float*)d_in[0];   // gt_boxes  [B, M, 4] xyxy
    const int*   lab = (const int*)d_in[1];     // labels    [B, M]
    const float* db  = (const float*)d_in[2];   // default_boxes [N, 4] xywh

    const int B = in_sizes[1] / M;
    const int N = in_sizes[2] / 4;
    const int nch = (N + 255) / 256;

    float* out_loc = (float*)d_out;                       // [B, N, 4]
    float* out_cls = out_loc + (size_t)B * N * 4;         // [B, N]

    unsigned long long* col = (unsigned long long*)d_ws;          // [B, M] u64
    float*              lbp = (float*)(col + (size_t)B * M);      // [B, M] f32

    const int total = nch * B;
    const int grid  = total < PERSIST_BLOCKS ? total : PERSIST_BLOCKS;

    lb_kernel<<<dim3(B * M), dim3(64), 0, stream>>>(gt, db, lbp, col);
    row_kernel<<<dim3(grid), dim3(256), 0, stream>>>(
        gt, lab, db, lbp, out_loc, out_cls, col, N, B, nch);
    fixup_kernel<<<dim3(B), dim3(M), 0, stream>>>(gt, lab, db, col, out_loc, out_cls, N);
}

// Round 13
// 98.752 us; speedup vs baseline: 1.4227x; 1.0666x over previous
//
#include <hip/hip_runtime.h>

#define M 64
#define FG_T 0.6f
#define BG_T 0.4f
#define PERSIST_BLOCKS 2048   // 8 blocks/CU x 256 CUs = device capacity at 16 VGPR

// packed column entry: (iou_bits << 32) | ~n — iou in (0,1] so the bit pattern
// is monotone; ties in iou resolve to SMALLER n (first occurrence = np argmax).
// 0 = "no entry"; fixup decodes p==0 -> anchor 0 (np argmax of an all-zero col).
//
// GT pack (written by lb_kernel, read via wave-uniform s_load in row_kernel):
//   pack[bm*2]   = {x0, y0, x1, y1}
//   pack[bm*2+1] = {area, lb, 0, 0}

// -------- lb kernel: per-(b,m) column-max lower bound + GT pack + ws init ------
// One wave per (b,m): lanes 0..53 each evaluate the EXACT iou (same op order
// as everywhere) of one of the 54 db anchors at the grid cell nearest the GT
// center (6 levels x 9 shapes); 6-step shuffle max. Each candidate is a real
// anchor's iou -> guaranteed lower bound on the column max; the nearest L5
// (384px) anchor always intersects, so lb > 0 for every GT.
__global__ __launch_bounds__(64) void lb_kernel(
    const float* __restrict__ gt,    // [B, M, 4] xyxy
    const float* __restrict__ db,    // [N, 4] xywh
    float4* __restrict__ pk,         // [B*M*2] GT pack
    unsigned long long* __restrict__ col)  // [B, M] — zero-initialized here
{
#pragma clang fp contract(off)
    const int bm = blockIdx.x;       // b*M + m
    const int t  = threadIdx.x;

    const float4 g = ((const float4*)gt)[bm];
    const float area_g = (g.z - g.x) * (g.w - g.y);   // reference op order
    const float gcx = (g.x + g.z) * 0.5f;
    const float gcy = (g.y + g.w) * 0.5f;

    const int   fms[6] = {64, 32, 16, 8, 4, 2};
    const float stp[6] = {8.0f, 16.0f, 32.0f, 64.0f, 128.0f, 256.0f};
    const int   off[6] = {0, 36864, 46080, 48384, 48960, 49104};

    float iou = 0.0f;
    if (t < 54) {
        const int lev = t / 9, a = t - lev * 9;
        const int fx  = fms[lev];
        int x = (int)(gcx / stp[lev]); x = min(max(x, 0), fx - 1);
        int y = (int)(gcy / stp[lev]); y = min(max(y, 0), fx - 1);
        const float4 d = ((const float4*)db)[off[lev] + (y * fx + x) * 9 + a];
        float ax0 = d.x - d.z / 2.0f;
        float ay0 = d.y - d.w / 2.0f;
        float ax1 = d.x + d.z / 2.0f;
        float ay1 = d.y + d.w / 2.0f;
        float area_a = (ax1 - ax0) * (ay1 - ay0);
        float w = fmaxf(fminf(ax1, g.z) - fmaxf(ax0, g.x), 0.0f);
        float h = fmaxf(fminf(ay1, g.w) - fmaxf(ay0, g.y), 0.0f);
        float inter = w * h;
        iou = inter / ((area_a + area_g) - inter);    // exact anchor iou
    }
    #pragma unroll
    for (int o = 1; o < 64; o <<= 1) iou = fmaxf(iou, __shfl_xor(iou, o));

    if (t == 0) {
        pk[(size_t)bm * 2]     = make_float4(g.x, g.y, g.z, g.w);
        pk[(size_t)bm * 2 + 1] = make_float4(area_g, iou, 0.0f, 0.0f);
        col[bm] = 0ull;
    }
}

// ------- row kernel: PERSISTENT grid-stride over (batch, chunk) units -------
// Persistent blocks keep ~8 waves/SIMD resident (TLP-saturated); remaining
// lever is VALU issue count per candidate. GT fragments come from the pack
// via wave-uniform index (readfirstlane) -> scalar-pipe s_load_dwordx4,
// replacing 13 v_readlane VALU slots per 2-GT iteration.
__global__ __launch_bounds__(256) void row_kernel(
    const float* __restrict__ gt,    // [B, M, 4] xyxy
    const int*   __restrict__ lab,   // [B, M]
    const float* __restrict__ db,    // [N, 4] xywh
    const float4* __restrict__ pk,   // [B*M*2] GT pack {xyxy},{area,lb,_,_}
    float* __restrict__ out_loc,     // [B, N, 4]
    float* __restrict__ out_cls,     // [B, N]
    unsigned long long* __restrict__ col,  // [B, M] packed column max
    int N, int B, int nch)           // nch = ceil(N/256)
{
#pragma clang fp contract(off)
    const int tid   = threadIdx.x;
    const int lane  = tid & 63;
    const int total = nch * B;

    for (int u = blockIdx.x; u < total; u += gridDim.x) {
        // chunk-major: u/B = reversed chunk (heavy coarse levels first), u%B = batch
        const unsigned uu = (unsigned)u;
        const int cm    = (int)(uu / (unsigned)B);
        const int b     = (int)(uu - (unsigned)cm * (unsigned)B);
        const int chunk = nch - 1 - cm;
        const int bM    = b * M;
        const float4* __restrict__ gtb = (const float4*)gt + bM;

        const int  n     = chunk * 256 + tid;
        const bool valid = (n < N);
        const int  nl    = valid ? n : (N - 1);

        const float4 d = ((const float4*)db)[nl];
        // db_xyxy exactly as reference: c - wh/2, c + wh/2 (div by 2 is exact)
        const float ax0 = d.x - d.z / 2.0f;
        const float ay0 = d.y - d.w / 2.0f;
        const float ax1 = d.x + d.z / 2.0f;
        const float ay1 = d.y + d.w / 2.0f;
        const float area_a = (ax1 - ax0) * (ay1 - ay0);

        // wave bbox (union of the wave's 64 anchors)
        float wx0 = ax0, wy0 = ay0, wx1 = ax1, wy1 = ay1;
        #pragma unroll
        for (int o = 1; o < 64; o <<= 1) {
            wx0 = fminf(wx0, __shfl_xor(wx0, o));
            wy0 = fminf(wy0, __shfl_xor(wy0, o));
            wx1 = fmaxf(wx1, __shfl_xor(wx1, o));
            wy1 = fmaxf(wy1, __shfl_xor(wy1, o));
        }

        // lane l tests GT l against the wave bbox; candidate iff strict overlap
        // (touch-only => inter==0 => iou==0 => irrelevant for row argmax and
        // column candidates since lb > 0).
        const float4 gl = gtb[lane];
        const bool cand = (gl.x < wx1) && (gl.z > wx0) && (gl.y < wy1) && (gl.w > wy0);
        unsigned long long mask = __ballot((int)cand);

        // best=0, bi=0: all-zero row keeps bi=0 (np argmax); strict > = first max.
        float best = 0.0f;
        int   bi   = 0;

        while (mask) {
            const int m0 = __builtin_amdgcn_readfirstlane(__builtin_ctzll(mask));
            mask &= mask - 1;
            const bool has2 = (mask != 0ull);
            const int m1 = has2 ? __builtin_amdgcn_readfirstlane(__builtin_ctzll(mask)) : m0;
            if (has2) mask &= mask - 1;

            // wave-uniform pack loads -> scalar pipe (s_load_dwordx4)
            const float4 pa0 = pk[(size_t)(bM + m0) * 2];
            const float4 pb0 = pk[(size_t)(bM + m0) * 2 + 1];
            const float4 pa1 = pk[(size_t)(bM + m1) * 2];
            const float4 pb1 = pk[(size_t)(bM + m1) * 2 + 1];

            // two independent intersection chains (no VCC hazard here)
            float i0 = fmaxf(fminf(ax1, pa0.z) - fmaxf(ax0, pa0.x), 0.0f)
                     * fmaxf(fminf(ay1, pa0.w) - fmaxf(ay0, pa0.y), 0.0f);
            float i1 = fmaxf(fminf(ax1, pa1.z) - fmaxf(ax0, pa1.x), 0.0f)
                     * fmaxf(fminf(ay1, pa1.w) - fmaxf(ay0, pa1.y), 0.0f);

            if (__any((i0 > 0.0f) || (i1 > 0.0f))) {
                // IEEE div: bit-exact vs np; inter==0 lanes get iou=+0.0 which
                // can neither beat best=0 (strict >) nor pass iou>=lb>0.
                float iou0 = i0 / ((area_a + pb0.x) - i0);
                float iou1 = i1 / ((area_a + pb1.x) - i1);

                // m0 < m1 always; process in order => first-occurrence argmax.
                if (iou0 > best)         { best = iou0; bi = m0; }
                if (has2 && iou1 > best) { best = iou1; bi = m1; }

                // Column candidates: iou >= lb[m] (lb <= column max by
                // construction) — catches the argmax and all earlier ties;
                // rare, so one combined wave-uniform guard.
                const bool c0 = valid && (iou0 >= pb0.y);
                const bool c1 = has2 && valid && (iou1 >= pb1.y);
                if (__any(c0 || c1)) {
                    if (c0) {
                        unsigned long long p =
                            (((unsigned long long)__float_as_uint(iou0)) << 32)
                            | (unsigned int)(~(unsigned int)n);
                        atomicMax(&col[bM + m0], p);
                    }
                    if (c1) {
                        unsigned long long p =
                            (((unsigned long long)__float_as_uint(iou1)) << 32)
                            | (unsigned int)(~(unsigned int)n);
                        atomicMax(&col[bM + m1], p);
                    }
                }
            }
        }

        if (valid) {
            float cv;
            if (best < BG_T)      cv = 0.0f;
            else if (best < FG_T) cv = -1.0f;
            else                  cv = (float)(lab[bM + bi] + 1);

            float4 g = gtb[bi];   // divergent gather, tiny table, L1-resident
            // rcp/log epilogue: ordering decided above; absmax threshold 3.54
            // vs ~1e-5 rcp error (validated r9-r11: absmax 0.03125 unchanged).
            float bcx = (g.x + g.z) * 0.5f;
            float bcy = (g.y + g.w) * 0.5f;
            float bw  = g.z - g.x;
            float bh  = g.w - g.y;
            float rz  = __builtin_amdgcn_rcpf(d.z);
            float rw  = __builtin_amdgcn_rcpf(d.w);
            float lx = (bcx - d.x) * rz * 10.0f;
            float ly = (bcy - d.y) * rw * 10.0f;
            float lw = __logf(bw * rz) * 5.0f;
            float lh = __logf(bh * rw) * 5.0f;

            ((float4*)out_loc)[(size_t)b * N + n] = make_float4(lx, ly, lw, lh);
            out_cls[(size_t)b * N + n] = cv;
        }
    }
}

// Apply the best_p_idx override: best_t_idx[best_p[m]] = m (last write wins),
// best_t -> 2.0 so cls = lab+1 and loc re-encoded from gt[m]. Separate dispatch:
// the kernel boundary provides cross-XCD coherence for free — fusing this with
// device-scope fences cost 4.5x (r7).
__global__ void fixup_kernel(
    const float* __restrict__ gt,
    const int*   __restrict__ lab,
    const float* __restrict__ db,
    const unsigned long long* __restrict__ col,
    float* __restrict__ out_loc,
    float* __restrict__ out_cls,
    int N)
{
#pragma clang fp contract(off)
    __shared__ int s_a[M];
    const int b = blockIdx.x;
    const int m = threadIdx.x;  // 64 threads

    unsigned long long p = col[b * M + m];
    // p==0: no anchor overlapped GT m -> np argmax of all-zero column = 0.
    int a = (p == 0ull) ? 0 : (int)(~(unsigned int)(p & 0xFFFFFFFFull));
    a = min(max(a, 0), N - 1);   // defensive clamp: no-op for kernel-produced values
    s_a[m] = a;
    __syncthreads();

    // last-write-wins for duplicate anchors (np fancy assignment semantics)
    bool write = true;
    for (int mm = m + 1; mm < M; ++mm) {
        if (s_a[mm] == a) { write = false; break; }
    }
    if (write) {
        float4 d = ((const float4*)db)[a];
        float4 g = ((const float4*)gt)[b * M + m];
        float bcx = (g.x + g.z) / 2.0f;
        float bcy = (g.y + g.w) / 2.0f;
        float bw  = g.z - g.x;
        float bh  = g.w - g.y;
        float lx = ((bcx - d.x) / d.z) / 0.1f;
        float ly = ((bcy - d.y) / d.w) / 0.1f;
        float lw = __logf(bw / d.z) / 0.2f;
        float lh = __logf(bh / d.w) / 0.2f;

        ((float4*)out_loc)[(size_t)b * N + a] = make_float4(lx, ly, lw, lh);
        out_cls[(size_t)b * N + a] = (float)(lab[b * M + m] + 1);  // best_t = 2.0
    }
}

extern "C" void kernel_launch(void* const* d_in, const int* in_sizes, int n_in,
                              void* d_out, int out_size, void* d_ws, size_t ws_size,
                              hipStream_t stream) {
    const float* gt  = (const float*)d_in[0];   // gt_boxes  [B, M, 4] xyxy
    const int*   lab = (const int*)d_in[1];     // labels    [B, M]
    const float* db  = (const float*)d_in[2];   // default_boxes [N, 4] xywh

    const int B = in_sizes[1] / M;
    const int N = in_sizes[2] / 4;
    const int nch = (N + 255) / 256;

    float* out_loc = (float*)d_out;                       // [B, N, 4]
    float* out_cls = out_loc + (size_t)B * N * 4;         // [B, N]

    unsigned long long* col = (unsigned long long*)d_ws;          // [B, M] u64
    float4*             pkp = (float4*)(col + (size_t)B * M);     // [B*M*2] f32x4

    const int total = nch * B;
    const int grid  = total < PERSIST_BLOCKS ? total : PERSIST_BLOCKS;

    lb_kernel<<<dim3(B * M), dim3(64), 0, stream>>>(gt, db, pkp, col);
    row_kernel<<<dim3(grid), dim3(256), 0, stream>>>(
        gt, lab, db, pkp, out_loc, out_cls, col, N, B, nch);
    fixup_kernel<<<dim3(B), dim3(M), 0, stream>>>(gt, lab, db, col, out_loc, out_cls, N);
}